// Round 7
// baseline (64.532 us; speedup 1.0000x reference)
//
#include <hip/hip_runtime.h>
#include <hip/hip_bf16.h>

#define B_SZ 256
#define N_SZ 2000
#define N_PAD 2048
#define D_SZ 512
#define C_SZ 100
#define BT 4           // batch rows per thread
#define D4 (D_SZ / 4)  // 128 float4 chunks per row
#define PF 4           // support prefetch depth (dc steps)
#define DSPLIT 2       // D split across blockIdx.z
#define DQ (D4 / DSPLIT) // 64 dc per block

// ---------------------------------------------------------------------------
// Prep: one-hot labels -> class index per support sample (no atomics)
// ---------------------------------------------------------------------------
__global__ void prep_kernel(const float* __restrict__ labels,
                            int* __restrict__ idx) {
    int n = blockIdx.x * 256 + threadIdx.x;
    if (n < N_SZ) {
        const float4* row = (const float4*)(labels + (size_t)n * C_SZ); // 25 float4
        int c = 0;
#pragma unroll
        for (int j = 0; j < C_SZ / 4; ++j) {
            float4 v = row[j];
            if (v.x > 0.5f) c = 4 * j + 0;
            if (v.y > 0.5f) c = 4 * j + 1;
            if (v.z > 0.5f) c = 4 * j + 2;
            if (v.w > 0.5f) c = 4 * j + 3;
        }
        idx[n] = c;
    }
}

// ---------------------------------------------------------------------------
// Transpose support [N][D4] float4 -> [D4][N_PAD] float4 (coalesced stream)
// ---------------------------------------------------------------------------
__global__ void transpose_kernel(const float4* __restrict__ sup4,
                                 float4* __restrict__ supT4) {
    int t = blockIdx.x * 256 + threadIdx.x; // t = dc * N_PAD + n
    int dc = t >> 11;                       // / N_PAD
    int n  = t & (N_PAD - 1);
    float4 v = make_float4(0.f, 0.f, 0.f, 0.f);
    if (n < N_SZ) v = sup4[(size_t)n * D4 + dc];
    supT4[t] = v;
}

// ---------------------------------------------------------------------------
// Main. Round-5/6 lesson: uniform inputs/w on the SCALAR pipe stall —
// streaming K$ misses + one scalar port/CU queue under occupancy, and
// SGPR budget (112) blocks software-pipelining. Fix: force these
// wave-uniform reads onto the VECTOR path (uniform addr = 1 txn, L1-hot,
// vmcnt-pipelined) via an opaque-zero VGPR mixed into the base pointers.
// Support stream keeps the named-register VMEM pipeline.
// ---------------------------------------------------------------------------
__global__ __launch_bounds__(256, 4) void score_kernel(
    const float4* __restrict__ inp4,   // [B][D4]
    const float4* __restrict__ supT4,  // [D4][N_PAD]
    const float4* __restrict__ w4,     // [D4]
    float* __restrict__ S)             // [DSPLIT][B][N_PAD] partial logits
{
    int tid = threadIdx.x;
    int n   = blockIdx.x * 256 + tid;
    int b0  = blockIdx.y * BT;
    int off = blockIdx.z * DQ;

    // Opaque zero in a VGPR: compiler cannot prove uniformity -> addresses
    // live in VGPRs -> global_load_dwordx4 (vector path), not s_load.
    unsigned vz = 0;
    asm volatile("" : "+v"(vz));

    const float4* __restrict__ a0 = inp4 + (size_t)(b0 + 0) * D4 + off + vz;
    const float4* __restrict__ a1 = inp4 + (size_t)(b0 + 1) * D4 + off + vz;
    const float4* __restrict__ a2 = inp4 + (size_t)(b0 + 2) * D4 + off + vz;
    const float4* __restrict__ a3 = inp4 + (size_t)(b0 + 3) * D4 + off + vz;
    const float4* __restrict__ wq = w4 + off + vz;

    const float4* __restrict__ sp = supT4 + (size_t)off * N_PAD + n;

    float acc[BT] = {0.f, 0.f, 0.f, 0.f};

    auto compute = [&](int dc, const float4& sv) {
        float4 wv = wq[dc];
        float4 av;
        av = a0[dc];
        acc[0] += wv.x * fabsf(av.x - sv.x);
        acc[0] += wv.y * fabsf(av.y - sv.y);
        acc[0] += wv.z * fabsf(av.z - sv.z);
        acc[0] += wv.w * fabsf(av.w - sv.w);
        av = a1[dc];
        acc[1] += wv.x * fabsf(av.x - sv.x);
        acc[1] += wv.y * fabsf(av.y - sv.y);
        acc[1] += wv.z * fabsf(av.z - sv.z);
        acc[1] += wv.w * fabsf(av.w - sv.w);
        av = a2[dc];
        acc[2] += wv.x * fabsf(av.x - sv.x);
        acc[2] += wv.y * fabsf(av.y - sv.y);
        acc[2] += wv.z * fabsf(av.z - sv.z);
        acc[2] += wv.w * fabsf(av.w - sv.w);
        av = a3[dc];
        acc[3] += wv.x * fabsf(av.x - sv.x);
        acc[3] += wv.y * fabsf(av.y - sv.y);
        acc[3] += wv.z * fabsf(av.z - sv.z);
        acc[3] += wv.w * fabsf(av.w - sv.w);
    };

    // Manual software pipeline: PF support chunks in flight in named regs.
    float4 c0 = sp[(size_t)0 * N_PAD];
    float4 c1 = sp[(size_t)1 * N_PAD];
    float4 c2 = sp[(size_t)2 * N_PAD];
    float4 c3 = sp[(size_t)3 * N_PAD];

#pragma unroll 1
    for (int dc = 0; dc < DQ - PF; dc += PF) {
        float4 t0 = sp[(size_t)(dc + 4) * N_PAD];
        float4 t1 = sp[(size_t)(dc + 5) * N_PAD];
        float4 t2 = sp[(size_t)(dc + 6) * N_PAD];
        float4 t3 = sp[(size_t)(dc + 7) * N_PAD];
        compute(dc + 0, c0);
        compute(dc + 1, c1);
        compute(dc + 2, c2);
        compute(dc + 3, c3);
        c0 = t0; c1 = t1; c2 = t2; c3 = t3;
    }
    compute(DQ - 4, c0);
    compute(DQ - 3, c1);
    compute(DQ - 2, c2);
    compute(DQ - 1, c3);

    float* __restrict__ Sz = S + ((size_t)blockIdx.z * B_SZ + b0) * N_PAD + n;
#pragma unroll
    for (int i = 0; i < BT; ++i)
        Sz[(size_t)i * N_PAD] = acc[i]; // coalesced; pad cols never read
}

// ---------------------------------------------------------------------------
// Aggregate: one block per batch row. Sum D-partials + bias -> sigmoid ->
// LDS class bins -> divide_no_nan. No global atomics, no pre-zeroing.
// ---------------------------------------------------------------------------
__global__ void agg_kernel(const float* __restrict__ S,
                           const int* __restrict__ idx,
                           const float* __restrict__ bias_p,
                           float* __restrict__ out) {
    __shared__ float sums[C_SZ];
    __shared__ float cnts[C_SZ];
    int b = blockIdx.x;
    int t = threadIdx.x;
    if (t < C_SZ) { sums[t] = 0.f; cnts[t] = 0.f; }
    __syncthreads();
    float bias = *bias_p;
    for (int n = t; n < N_SZ; n += 256) {
        float logit = bias;
#pragma unroll
        for (int z = 0; z < DSPLIT; ++z)
            logit += S[((size_t)z * B_SZ + b) * N_PAD + n];
        float s = 1.0f / (1.0f + __expf(-logit));
        int c = idx[n];
        atomicAdd(&sums[c], s);
        atomicAdd(&cnts[c], 1.0f);
    }
    __syncthreads();
    if (t < C_SZ) {
        float cnt = cnts[t];
        out[(size_t)b * C_SZ + t] = (cnt != 0.f) ? sums[t] / cnt : 0.f;
    }
}

extern "C" void kernel_launch(void* const* d_in, const int* in_sizes, int n_in,
                              void* d_out, int out_size, void* d_ws, size_t ws_size,
                              hipStream_t stream) {
    const float* inputs  = (const float*)d_in[0]; // [B, D]
    const float* support = (const float*)d_in[1]; // [N, D]
    const float* labels  = (const float*)d_in[2]; // [N, C]
    const float* w       = (const float*)d_in[3]; // [D]
    const float* bias    = (const float*)d_in[4]; // [1]
    float* out = (float*)d_out;                   // [B, C]

    // Workspace: idx[2048] @0 (8KB, fully written by prep), pad to 16KB,
    // supT4 @16KB (4MB), S @16KB+4MB (DSPLIT*2MB = 4MB). No zeroing needed.
    int*    idx   = (int*)d_ws;
    float4* supT4 = (float4*)((char*)d_ws + 16384);
    float*  S     = (float*)((char*)d_ws + 16384 + (size_t)D4 * N_PAD * sizeof(float4));

    prep_kernel<<<dim3((N_SZ + 255) / 256), dim3(256), 0, stream>>>(labels, idx);

    transpose_kernel<<<dim3(D4 * N_PAD / 256), dim3(256), 0, stream>>>(
        (const float4*)support, supT4);

    dim3 grid(N_PAD / 256, B_SZ / BT, DSPLIT); // 8 x 64 x 2 = 1024 blocks
    score_kernel<<<grid, dim3(256), 0, stream>>>(
        (const float4*)inputs, supT4, (const float4*)w, S);

    agg_kernel<<<dim3(B_SZ), dim3(256), 0, stream>>>(S, idx, bias, out);
}

// Round 8
// 46.660 us; speedup vs baseline: 1.3830x; 1.3830x over previous
//
#include <hip/hip_runtime.h>
#include <hip/hip_bf16.h>

#define B_SZ 256
#define N_SZ 2000
#define N_PAD 2048
#define D_SZ 512
#define C_SZ 100
#define BT 4            // batch rows per block
#define DC 8            // float4 per d-chunk (32 floats)
#define NH 2            // d-chunks per block (sequential, RMW-accumulated)
#define ZSPLIT 8        // blockIdx.y slices -> S_part[ZSPLIT][B][N_PAD]
#define D4 (D_SZ / 4)   // 128 float4 per row

// ---------------------------------------------------------------------------
// Prep: one-hot labels -> class index per support sample (no atomics)
// ---------------------------------------------------------------------------
__global__ void prep_kernel(const float* __restrict__ labels,
                            int* __restrict__ idx) {
    int n = blockIdx.x * 256 + threadIdx.x;
    if (n < N_SZ) {
        const float4* row = (const float4*)(labels + (size_t)n * C_SZ);
        int c = 0;
#pragma unroll
        for (int j = 0; j < C_SZ / 4; ++j) {
            float4 v = row[j];
            if (v.x > 0.5f) c = 4 * j + 0;
            if (v.y > 0.5f) c = 4 * j + 1;
            if (v.z > 0.5f) c = 4 * j + 2;
            if (v.w > 0.5f) c = 4 * j + 3;
        }
        idx[n] = c;
    }
}

// ---------------------------------------------------------------------------
// Transpose support [N][D4] float4 -> [D4][N_PAD] float4 (coalesced stream)
// ---------------------------------------------------------------------------
__global__ void transpose_kernel(const float4* __restrict__ sup4,
                                 float4* __restrict__ supT4) {
    int t = blockIdx.x * 256 + threadIdx.x; // t = dc * N_PAD + n
    int dc = t >> 11;
    int n  = t & (N_PAD - 1);
    float4 v = make_float4(0.f, 0.f, 0.f, 0.f);
    if (n < N_SZ) v = sup4[(size_t)n * D4 + dc];
    supT4[t] = v;
}

// ---------------------------------------------------------------------------
// Main (n-sweep). Rounds 4-7 lesson: re-reading wave-uniform inputs/w every
// inner iteration loses on EVERY pipe (LDS / scalar K$ / vector L1). Fix:
// each block owns (BT batch rows x NH*DC*4 d's); inputs+w loaded ONCE into
// VGPRs (vz trick forces vector regs), then sweep n: steady state is only
// the coalesced support stream (prefetched one step ahead) + pure VALU +
// coalesced stores. h=0 stores partials, h=1 RMW-adds (same thread, same
// address -> deterministic, no atomics).
// ---------------------------------------------------------------------------
__global__ __launch_bounds__(256, 2) void score_kernel(
    const float4* __restrict__ inp4,   // [B][D4]
    const float4* __restrict__ supT4,  // [D4][N_PAD]
    const float4* __restrict__ w4,     // [D4]
    float* __restrict__ S)             // [ZSPLIT][B][N_PAD] partial logits
{
    int tid = threadIdx.x;
    int b0  = blockIdx.x * BT;
    float* __restrict__ Sp0 =
        S + ((size_t)blockIdx.y * B_SZ + b0) * N_PAD + tid;

#pragma unroll 1
    for (int h = 0; h < NH; ++h) {
        int dq = blockIdx.y * (NH * DC) + h * DC; // float4 index into D4

        // Opaque zero in a VGPR: forces inp/w into vector registers
        // (compiler can't prove uniformity -> no SGPR allocation blowup).
        unsigned vz = 0;
        asm volatile("" : "+v"(vz));

        float4 af[BT][DC];
        float4 wf[DC];
#pragma unroll
        for (int i = 0; i < BT; ++i) {
            const float4* __restrict__ ab = inp4 + (size_t)(b0 + i) * D4 + dq + vz;
#pragma unroll
            for (int j = 0; j < DC; ++j) af[i][j] = ab[j];
        }
        {
            const float4* __restrict__ wb = w4 + dq + vz;
#pragma unroll
            for (int j = 0; j < DC; ++j) wf[j] = wb[j];
        }

        const float4* __restrict__ sp = supT4 + (size_t)dq * N_PAD + tid;

        // --- software-pipelined n-sweep: prefetch next 64-n column group ---
        float4 sv[DC], nx[DC];
#pragma unroll
        for (int j = 0; j < DC; ++j) sv[j] = sp[(size_t)j * N_PAD];

#pragma unroll 1
        for (int n0 = 0; n0 < N_PAD - 256; n0 += 256) {
#pragma unroll
            for (int j = 0; j < DC; ++j)
                nx[j] = sp[(size_t)j * N_PAD + (n0 + 256)];

            float acc[BT] = {0.f, 0.f, 0.f, 0.f};
#pragma unroll
            for (int j = 0; j < DC; ++j) {
#pragma unroll
                for (int i = 0; i < BT; ++i) {
                    acc[i] += wf[j].x * fabsf(af[i][j].x - sv[j].x);
                    acc[i] += wf[j].y * fabsf(af[i][j].y - sv[j].y);
                    acc[i] += wf[j].z * fabsf(af[i][j].z - sv[j].z);
                    acc[i] += wf[j].w * fabsf(af[i][j].w - sv[j].w);
                }
            }

            float* Sp = Sp0 + n0;
            if (h == 0) {
#pragma unroll
                for (int i = 0; i < BT; ++i) Sp[(size_t)i * N_PAD] = acc[i];
            } else {
#pragma unroll
                for (int i = 0; i < BT; ++i) Sp[(size_t)i * N_PAD] += acc[i];
            }
#pragma unroll
            for (int j = 0; j < DC; ++j) sv[j] = nx[j];
        }

        // epilogue step (n0 = N_PAD-256), no prefetch
        {
            float acc[BT] = {0.f, 0.f, 0.f, 0.f};
#pragma unroll
            for (int j = 0; j < DC; ++j) {
#pragma unroll
                for (int i = 0; i < BT; ++i) {
                    acc[i] += wf[j].x * fabsf(af[i][j].x - sv[j].x);
                    acc[i] += wf[j].y * fabsf(af[i][j].y - sv[j].y);
                    acc[i] += wf[j].z * fabsf(af[i][j].z - sv[j].z);
                    acc[i] += wf[j].w * fabsf(af[i][j].w - sv[j].w);
                }
            }
            float* Sp = Sp0 + (N_PAD - 256);
            if (h == 0) {
#pragma unroll
                for (int i = 0; i < BT; ++i) Sp[(size_t)i * N_PAD] = acc[i];
            } else {
#pragma unroll
                for (int i = 0; i < BT; ++i) Sp[(size_t)i * N_PAD] += acc[i];
            }
        }
    }
}

// ---------------------------------------------------------------------------
// Aggregate: one block per batch row. Sum ZSPLIT partials + bias -> sigmoid
// -> LDS class bins -> divide_no_nan. No global atomics, no pre-zeroing.
// ---------------------------------------------------------------------------
__global__ void agg_kernel(const float* __restrict__ S,
                           const int* __restrict__ idx,
                           const float* __restrict__ bias_p,
                           float* __restrict__ out) {
    __shared__ float sums[C_SZ];
    __shared__ float cnts[C_SZ];
    int b = blockIdx.x;
    int t = threadIdx.x;
    if (t < C_SZ) { sums[t] = 0.f; cnts[t] = 0.f; }
    __syncthreads();
    float bias = *bias_p;
    for (int n = t; n < N_SZ; n += 256) {
        float logit = bias;
#pragma unroll
        for (int z = 0; z < ZSPLIT; ++z)
            logit += S[((size_t)z * B_SZ + b) * N_PAD + n];
        float s = 1.0f / (1.0f + __expf(-logit));
        int c = idx[n];
        atomicAdd(&sums[c], s);
        atomicAdd(&cnts[c], 1.0f);
    }
    __syncthreads();
    if (t < C_SZ) {
        float cnt = cnts[t];
        out[(size_t)b * C_SZ + t] = (cnt != 0.f) ? sums[t] / cnt : 0.f;
    }
}

extern "C" void kernel_launch(void* const* d_in, const int* in_sizes, int n_in,
                              void* d_out, int out_size, void* d_ws, size_t ws_size,
                              hipStream_t stream) {
    const float* inputs  = (const float*)d_in[0]; // [B, D]
    const float* support = (const float*)d_in[1]; // [N, D]
    const float* labels  = (const float*)d_in[2]; // [N, C]
    const float* w       = (const float*)d_in[3]; // [D]
    const float* bias    = (const float*)d_in[4]; // [1]
    float* out = (float*)d_out;                   // [B, C]

    // Workspace: idx[2048] @0 (8KB), pad to 16KB, supT4 @16KB (4MB),
    // S @16KB+4MB (ZSPLIT * 2MB = 16MB). No zeroing needed (S slot z is
    // fully written by block y=z at h=0 before h=1/agg read it).
    int*    idx   = (int*)d_ws;
    float4* supT4 = (float4*)((char*)d_ws + 16384);
    float*  S     = (float*)((char*)d_ws + 16384 + (size_t)D4 * N_PAD * sizeof(float4));

    prep_kernel<<<dim3((N_SZ + 255) / 256), dim3(256), 0, stream>>>(labels, idx);

    transpose_kernel<<<dim3(D4 * N_PAD / 256), dim3(256), 0, stream>>>(
        (const float4*)support, supT4);

    dim3 grid(B_SZ / BT, ZSPLIT); // 64 x 8 = 512 blocks, 2 waves/SIMD
    score_kernel<<<grid, dim3(256), 0, stream>>>(
        (const float4*)inputs, supT4, (const float4*)w, S);

    agg_kernel<<<dim3(B_SZ), dim3(256), 0, stream>>>(S, idx, bias, out);
}

// Round 10
// 42.074 us; speedup vs baseline: 1.5338x; 1.1090x over previous
//
#include <hip/hip_runtime.h>

#define B_SZ 256
#define N_SZ 2000
#define N_PAD 2048
#define D_SZ 512
#define C_SZ 100
#define BT 4             // batch rows per block
#define JW 4             // H8 groups (8 d's each) per block = 32 d's
#define ZSPLIT 16        // D_SZ / 32
#define D4 (D_SZ / 4)
#define DC8 (D_SZ / 8)   // 64 H8 rows in supH

typedef __fp16 h2 __attribute__((ext_vector_type(2)));

struct alignas(16) H8 { h2 x, y, z, w; };  // 8 consecutive halves
struct alignas(8)  H4 { h2 lo, hi; };      // 4 consecutive halves

static __device__ __forceinline__ h2 habs2(h2 v) {
    unsigned u = __builtin_bit_cast(unsigned, v) & 0x7FFF7FFFu;
    return __builtin_bit_cast(h2, u);
}

#if __has_builtin(__builtin_amdgcn_fdot2)
static __device__ __forceinline__ float DOT2(h2 d, h2 wv, float c) {
    return __builtin_amdgcn_fdot2(d, wv, c, false);
}
#else
static __device__ __forceinline__ float DOT2(h2 d, h2 wv, float c) {
    return c + (float)d.x * (float)wv.x + (float)d.y * (float)wv.y;
}
#endif

// ---------------------------------------------------------------------------
// Setup (fused): labels->idx | w->f16 | inputs->f16
// ---------------------------------------------------------------------------
__global__ void setup_kernel(const float* __restrict__ labels,
                             const float* __restrict__ inputs,
                             const float* __restrict__ w,
                             int* __restrict__ idx,
                             H4* __restrict__ inpH4,
                             __fp16* __restrict__ wH) {
    int bid = blockIdx.x, tid = threadIdx.x;
    if (bid < 8) {                       // label scan -> class index
        int n = bid * 256 + tid;
        if (n < N_SZ) {
            const float4* row = (const float4*)(labels + (size_t)n * C_SZ);
            int c = 0;
#pragma unroll
            for (int j = 0; j < C_SZ / 4; ++j) {
                float4 v = row[j];
                if (v.x > 0.5f) c = 4 * j + 0;
                if (v.y > 0.5f) c = 4 * j + 1;
                if (v.z > 0.5f) c = 4 * j + 2;
                if (v.w > 0.5f) c = 4 * j + 3;
            }
            idx[n] = c;
        }
    } else if (bid == 8) {               // w convert
        wH[tid]       = (__fp16)w[tid];
        wH[tid + 256] = (__fp16)w[tid + 256];
    } else {                             // inputs convert (float4 -> H4)
        int i4 = (bid - 9) * 256 + tid;  // 32768 float4s -> 128 blocks
        float4 v = ((const float4*)inputs)[i4];
        H4 o;
        o.lo = __builtin_amdgcn_cvt_pkrtz(v.x, v.y);
        o.hi = __builtin_amdgcn_cvt_pkrtz(v.z, v.w);
        inpH4[i4] = o;
    }
}

// ---------------------------------------------------------------------------
// Transpose+convert support: [N][D] f32 -> supH[DC8][N_PAD] H8 (8 d's/elem),
// so score's per-lane stream is coalesced 16B covering 8 dims.
// ---------------------------------------------------------------------------
__global__ void transposeH_kernel(const float4* __restrict__ sup4,
                                  H8* __restrict__ supH) {
    int t = blockIdx.x * 256 + threadIdx.x; // t = dc8 * N_PAD + n
    int dc8 = t >> 11;
    int n   = t & (N_PAD - 1);
    H8 o = {};
    if (n < N_SZ) {
        float4 p = sup4[(size_t)n * D4 + 2 * dc8];
        float4 q = sup4[(size_t)n * D4 + 2 * dc8 + 1];
        o.x = __builtin_amdgcn_cvt_pkrtz(p.x, p.y);
        o.y = __builtin_amdgcn_cvt_pkrtz(p.z, p.w);
        o.z = __builtin_amdgcn_cvt_pkrtz(q.x, q.y);
        o.w = __builtin_amdgcn_cvt_pkrtz(q.z, q.w);
    }
    supH[t] = o;
}

// ---------------------------------------------------------------------------
// Main (n-sweep, f16 packed). Block owns BT=4 batch rows x 32 d's; inputs+w
// live in VGPRs (vz trick), support stream coalesced + prefetched one n-step
// ahead per j-row. Inner math: pk_sub + and(abs) + v_dot2_f32_f16 =
// 1.5 instr/elem with f32 accumulation. Partials to S[ZSPLIT][B][N_PAD].
// ---------------------------------------------------------------------------
__global__ __launch_bounds__(256, 3) void score_kernel(
    const H8* __restrict__ inpH8,   // [B][DC8]
    const H8* __restrict__ supH,    // [DC8][N_PAD]
    const H8* __restrict__ wH8,     // [DC8]
    float* __restrict__ S)          // [ZSPLIT][B][N_PAD]
{
    int tid = threadIdx.x;
    int b0  = blockIdx.x * BT;
    int dc0 = blockIdx.y * JW;      // H8-row base (32 d's)

    // Opaque zero in VGPR: forces inp/w into vector regs (one-time loads).
    unsigned vz = 0;
    asm volatile("" : "+v"(vz));

    H8 af[BT][JW];
    H8 wf[JW];
#pragma unroll
    for (int i = 0; i < BT; ++i) {
        const H8* ap = inpH8 + (size_t)(b0 + i) * DC8 + dc0 + vz;
#pragma unroll
        for (int j = 0; j < JW; ++j) af[i][j] = ap[j];
    }
    {
        const H8* wp = wH8 + dc0 + vz;
#pragma unroll
        for (int j = 0; j < JW; ++j) wf[j] = wp[j];
    }

    const H8* sp0 = supH + (size_t)(dc0 + 0) * N_PAD + tid;
    const H8* sp1 = supH + (size_t)(dc0 + 1) * N_PAD + tid;
    const H8* sp2 = supH + (size_t)(dc0 + 2) * N_PAD + tid;
    const H8* sp3 = supH + (size_t)(dc0 + 3) * N_PAD + tid;

    float* Sp0 = S + ((size_t)blockIdx.y * B_SZ + b0) * N_PAD + tid;

#define STEP(J, SV)                                                  \
    {                                                                \
        H8 wv = wf[J];                                               \
        _Pragma("unroll") for (int i = 0; i < BT; ++i) {             \
            H8 a = af[i][J];                                         \
            acc[i] = DOT2(habs2(a.x - SV.x), wv.x, acc[i]);          \
            acc[i] = DOT2(habs2(a.y - SV.y), wv.y, acc[i]);          \
            acc[i] = DOT2(habs2(a.z - SV.z), wv.z, acc[i]);          \
            acc[i] = DOT2(habs2(a.w - SV.w), wv.w, acc[i]);          \
        }                                                            \
    }

    H8 sv0 = sp0[0], sv1 = sp1[0], sv2 = sp2[0], sv3 = sp3[0];

#pragma unroll 1
    for (int n0 = 0; n0 < N_PAD - 256; n0 += 256) {
        float acc[BT] = {0.f, 0.f, 0.f, 0.f};
        // rolling prefetch: issue next j-row load, then compute current j-row
        H8 nx0 = sp0[n0 + 256];
        STEP(0, sv0);
        H8 nx1 = sp1[n0 + 256];
        STEP(1, sv1);
        H8 nx2 = sp2[n0 + 256];
        STEP(2, sv2);
        H8 nx3 = sp3[n0 + 256];
        STEP(3, sv3);
#pragma unroll
        for (int i = 0; i < BT; ++i)
            Sp0[(size_t)i * N_PAD + n0] = acc[i];
        sv0 = nx0; sv1 = nx1; sv2 = nx2; sv3 = nx3;
    }
    {   // epilogue n-step
        float acc[BT] = {0.f, 0.f, 0.f, 0.f};
        STEP(0, sv0); STEP(1, sv1); STEP(2, sv2); STEP(3, sv3);
#pragma unroll
        for (int i = 0; i < BT; ++i)
            Sp0[(size_t)i * N_PAD + (N_PAD - 256)] = acc[i];
    }
#undef STEP
}

// ---------------------------------------------------------------------------
// Aggregate: one 512-thread block per batch row. Sum 16 partials + bias ->
// sigmoid -> LDS class bins -> divide_no_nan.
// ---------------------------------------------------------------------------
__global__ void agg_kernel(const float* __restrict__ S,
                           const int* __restrict__ idx,
                           const float* __restrict__ bias_p,
                           float* __restrict__ out) {
    __shared__ float sums[C_SZ];
    __shared__ float cnts[C_SZ];
    int b = blockIdx.x;
    int t = threadIdx.x;
    if (t < C_SZ) { sums[t] = 0.f; cnts[t] = 0.f; }
    __syncthreads();
    float bias = *bias_p;
    for (int n = t; n < N_SZ; n += 512) {
        float logit = bias;
#pragma unroll
        for (int z = 0; z < ZSPLIT; ++z)
            logit += S[((size_t)z * B_SZ + b) * N_PAD + n];
        float s = 1.0f / (1.0f + __expf(-logit));
        int c = idx[n];
        atomicAdd(&sums[c], s);
        atomicAdd(&cnts[c], 1.0f);
    }
    __syncthreads();
    if (t < C_SZ) {
        float cnt = cnts[t];
        out[(size_t)b * C_SZ + t] = (cnt != 0.f) ? sums[t] / cnt : 0.f;
    }
}

extern "C" void kernel_launch(void* const* d_in, const int* in_sizes, int n_in,
                              void* d_out, int out_size, void* d_ws, size_t ws_size,
                              hipStream_t stream) {
    const float* inputs  = (const float*)d_in[0]; // [B, D]
    const float* support = (const float*)d_in[1]; // [N, D]
    const float* labels  = (const float*)d_in[2]; // [N, C]
    const float* w       = (const float*)d_in[3]; // [D]
    const float* bias    = (const float*)d_in[4]; // [1]
    float* out = (float*)d_out;                   // [B, C]

    // ws layout (bytes): idx@0 (8K) | wH@8K (1K) | inpH@16K (256K) |
    // supH@512K (2M) | S@4M (32M). All regions fully written before read.
    int*     idx  = (int*)d_ws;
    __fp16*  wH   = (__fp16*)((char*)d_ws + 8192);
    __fp16*  inpH = (__fp16*)((char*)d_ws + 16384);
    H8*      supH = (H8*)((char*)d_ws + 524288);
    float*   S    = (float*)((char*)d_ws + 4 * 1024 * 1024);

    setup_kernel<<<dim3(9 + B_SZ * D_SZ / 4 / 256), dim3(256), 0, stream>>>(
        labels, inputs, w, idx, (H4*)inpH, wH);

    transposeH_kernel<<<dim3(DC8 * N_PAD / 256), dim3(256), 0, stream>>>(
        (const float4*)support, supH);

    dim3 grid(B_SZ / BT, ZSPLIT); // 64 x 16 = 1024 blocks
    score_kernel<<<grid, dim3(256), 0, stream>>>(
        (const H8*)inpH, supH, (const H8*)wH, S);

    agg_kernel<<<dim3(B_SZ), dim3(512), 0, stream>>>(S, idx, bias, out);
}